// Round 6
// baseline (385.441 us; speedup 1.0000x reference)
//
#include <hip/hip_runtime.h>

#define PS 32
#define NPIX (PS * PS)
#define NB 36
#define WPB 4      // waves per block
#define TPW 8      // patches per wave (grid sizing target)
#define FCAP 64    // deferred-fixup list capacity per wave

// ---------------------------------------------------------------------------
// Init kernel: gk10[p] = float32(10 * CircularGaussKernel(32)) computed in f64,
// replicating numpy linspace + exp + normalize semantics, then cast to f32.
// ---------------------------------------------------------------------------
__global__ __launch_bounds__(256) void gk_init_kernel(float* __restrict__ gk10) {
    __shared__ double red[256];
    const int tid = threadIdx.x;
    const double delta = 32.0 / 31.0;       // numpy linspace step, f64
    const double sigma2 = 0.9 * 256.0;      // 0.9 * half^2, f64

    double kv[4];
    double s = 0.0;
#pragma unroll
    for (int j = 0; j < 4; ++j) {
        int p = tid * 4 + j;
        int r = p >> 5, c = p & 31;
        double xr = (r == 31) ? 16.0 : ((double)r * delta + (-16.0));
        double xc = (c == 31) ? 16.0 : ((double)c * delta + (-16.0));
        double d2 = xc * xc + xr * xr;
        kv[j] = exp(-d2 / sigma2);
        s += kv[j];
    }
    red[tid] = s;
    __syncthreads();
    for (int off = 128; off > 0; off >>= 1) {
        if (tid < off) red[tid] += red[tid + off];
        __syncthreads();
    }
    double sum = red[0];
#pragma unroll
    for (int j = 0; j < 4; ++j) {
        int p = tid * 4 + j;
        gk10[p] = __fmul_rn(10.0f, (float)(kv[j] / sum));
    }
}

// ---------------------------------------------------------------------------
// Main kernel: PERSISTENT waves. 8192 waves total; each wave grid-strides
// over ~8 patches, prefetching the NEXT patch's global data into registers
// while computing the CURRENT patch from LDS. Exposes global-memory latency
// once per wave instead of once per patch. Math/tail identical to round 5
// (proven exact).
// ---------------------------------------------------------------------------
__global__ __launch_bounds__(256) void orient_kernel(const float* __restrict__ x,
                                                     const float* __restrict__ gk10,
                                                     float* __restrict__ out,
                                                     int B) {
    const float PI_F    = 3.14159265358979323846f;   // 0x40490FDB
    const float TWOPI_F = 6.28318530717958647692f;   // 0x40C90FDB

    __shared__ __align__(16) float tile[WPB][NPIX];
    __shared__ float hist[WPB][NB];
    __shared__ int   nflag[WPB];
    __shared__ int   flagp[WPB][FCAP];

    const int tid = threadIdx.x;
    const int w = tid >> 6;          // wave id within block
    const int l = tid & 63;          // lane within wave
    const int nw = gridDim.x * WPB;  // total waves in grid

    float* tw = tile[w];
    float* hw = hist[w];
    float4* dst = reinterpret_cast<float4*>(tw);

    const int r  = l >> 3;           // row within each 8-row band
    const int c0 = (l & 7) << 2;     // col 0,4,...,28

    // Gaussian weights: loaded once per wave (same for all patches)
    float4 gkq[4];
#pragma unroll
    for (int k = 0; k < 4; ++k)
        gkq[k] = *reinterpret_cast<const float4*>(&gk10[(k * 8 + r) * PS + c0]);

    int patch = blockIdx.x * WPB + w;
    if (patch >= B) return;

    // Prologue: prefetch first patch into registers
    float4 nxt[4];
    {
        const float4* src = reinterpret_cast<const float4*>(x + (size_t)patch * NPIX);
#pragma unroll
        for (int k = 0; k < 4; ++k) nxt[k] = src[k * 64 + l];
    }

    for (; patch < B; patch += nw) {
        // ---- Stage current patch (in nxt) into LDS; init hist + flag count
#pragma unroll
        for (int k = 0; k < 4; ++k) dst[k * 64 + l] = nxt[k];
        if (l < NB) hw[l] = 0.0f;
        if (l == 0) nflag[w] = 0;

        // ---- Prefetch NEXT patch into registers (flies during compute)
        const int np = patch + nw;
        if (np < B) {
            const float4* src = reinterpret_cast<const float4*>(x + (size_t)np * NPIX);
#pragma unroll
            for (int k = 0; k < 4; ++k) nxt[k] = src[k * 64 + l];
        }

        // staging ds_writes complete before reading (same wave, lockstep)
        asm volatile("s_waitcnt lgkmcnt(0)" ::: "memory");

        // ---- Batched neighbor reads from LDS (incl. self rows)
        float4 sf[4], up[4], dn[4];
        float  lsc[4], rsc[4];
#pragma unroll
        for (int k = 0; k < 4; ++k) {
            const int row = k * 8 + r;
            const int rowOff = row << 5;
            const int upOff  = ((row == 0)  ? 0  : (row - 1)) << 5;   // replicate pad
            const int dnOff  = ((row == 31) ? 31 : (row + 1)) << 5;
            sf[k]  = *reinterpret_cast<const float4*>(&tw[rowOff + c0]);
            up[k]  = *reinterpret_cast<const float4*>(&tw[upOff + c0]);
            dn[k]  = *reinterpret_cast<const float4*>(&tw[dnOff + c0]);
            lsc[k] = tw[rowOff + ((c0 == 0) ? 0 : (c0 - 1))];
            rsc[k] = tw[rowOff + ((c0 + 4 > 31) ? 31 : (c0 + 4))];
        }

        // ======================= STAGE A =======================
        float rrs[16], magv[16], cbv[16];
#pragma unroll
        for (int k = 0; k < 4; ++k) {
            float sv[4]  = {sf[k].x, sf[k].y, sf[k].z, sf[k].w};
            float uv[4]  = {up[k].x, up[k].y, up[k].z, up[k].w};
            float dv[4]  = {dn[k].x, dn[k].y, dn[k].z, dn[k].w};
            float gk4[4] = {gkq[k].x, gkq[k].y, gkq[k].z, gkq[k].w};
            float lv[4]  = {lsc[k], sv[0], sv[1], sv[2]};
            float rv[4]  = {sv[1],  sv[2], sv[3], rsc[k]};
#pragma unroll
            for (int j = 0; j < 4; ++j) {
                const int i = k * 4 + j;
                // Reference f32 op order for magnitude (no contraction):
                float gx = __fmul_rn(0.5f, __fsub_rn(lv[j], rv[j]));
                float gy = __fmul_rn(0.5f, __fsub_rn(uv[j], dv[j]));
                float s2 = __fadd_rn(__fadd_rn(__fmul_rn(gx, gx), __fmul_rn(gy, gy)), 1e-10f);
                magv[i] = __fmul_rn(__fsqrt_rn(s2), gk4[j]);

                float ax = fabsf(gx), ay = fabsf(gy);
                float mn = fminf(ax, ay), mx = fmaxf(ax, ay);
                float rr = mn * __builtin_amdgcn_rcpf(mx);   // ~1 ulp
                rr = (mx > 0.0f) ? rr : 0.0f;                // atan2(0,0) = 0

                // Quadrant folding: obig = S*atan_bins(rr) + Cb (exact ints)
                bool c1 = ay > ax;
                bool c2 = gx < 0.0f;
                bool c3 = gy < 0.0f;
                float S  = c1 ? -1.0f : 1.0f;
                float Cb = c1 ? 27.0f : 18.0f;
                S  = c2 ? -S : S;
                Cb = c2 ? __fsub_rn(54.0f, Cb) : Cb;
                S  = c3 ? -S : S;
                Cb = c3 ? __fsub_rn(36.0f, Cb) : Cb;
                rrs[i] = rr * S;                       // exact (S = +/-1)
                cbv[i] = Cb;
            }
        }

        // ======================= STAGE B =======================
        const float BINSCALE = 5.72957795130823208768f;   // 18/pi
#pragma unroll
        for (int i = 0; i < 16; ++i) {
            float rr = rrs[i];
            float t  = rr * rr;
            float u = 0.00282363896258175373077393f;      // SLEEF deg-17 odd minimax
            u = fmaf(u, t, -0.0159569028764963150024414f);
            u = fmaf(u, t,  0.0425049886107444763183594f);
            u = fmaf(u, t, -0.0748900920152664184570312f);
            u = fmaf(u, t,  0.106347933411598205566406f);
            u = fmaf(u, t, -0.142027363181114196777344f);
            u = fmaf(u, t,  0.199926957488059997558594f);
            u = fmaf(u, t, -0.333331018686294555664062f);
            float at   = fmaf(rr * t, u, rr);             // odd: at(-x) = -at(x)
            float obig = fmaf(at, BINSCALE, cbv[i]);      // [0, 36]
            float bo0f = floorf(obig);
            float wo1  = __fsub_rn(obig, bo0f);

            bool bad = (wo1 < 2e-5f) | (wo1 > 1.0f - 2e-5f);
            if (!bad) {
                int bo = (int)bo0f;
                if (bo >= NB) bo -= NB;
                float wo0 = __fmul_rn(__fsub_rn(1.0f, wo1), magv[i]);
                atomicAdd(&hw[bo], wo0);
            } else {
                int idx = atomicAdd(&nflag[w], 1);
                const int row = (i >> 2) * 8 + r;
                if (idx < FCAP) flagp[w][idx] = (row << 5) + c0 + (i & 3);
            }
        }
        asm volatile("s_waitcnt lgkmcnt(0)" ::: "memory");

        // ---- Exact f64 fixup for flagged pixels (~0.04 expected per patch)
        int nf = nflag[w];
        if (nf > FCAP) nf = FCAP;
        for (int s = l; s < nf; s += 64) {
            int p = flagp[w][s];
            int rr2 = p >> 5, cc = p & 31;
            float cl = tw[p - (cc > 0 ? 1 : 0)];
            float cr = tw[p + (cc < 31 ? 1 : 0)];
            float cu = tw[p - (rr2 > 0 ? 32 : 0)];
            float cd = tw[p + (rr2 < 31 ? 32 : 0)];
            float gx = __fmul_rn(0.5f, __fsub_rn(cl, cr));
            float gy = __fmul_rn(0.5f, __fsub_rn(cu, cd));
            float s2 = __fadd_rn(__fadd_rn(__fmul_rn(gx, gx), __fmul_rn(gy, gy)), 1e-10f);
            float mag = __fmul_rn(__fsqrt_rn(s2), gk10[p]);

            float ori  = (float)atan2((double)gy, (double)gx);  // correctly-rounded f32
            float obig = __fdiv_rn(__fmul_rn(36.0f, __fadd_rn(ori, PI_F)), TWOPI_F);
            float bo0f = floorf(obig);
            float wo1  = __fsub_rn(obig, bo0f);
            int bo = (int)bo0f;
            if (bo >= NB) bo -= NB;
            float wo0 = __fmul_rn(__fsub_rn(1.0f, wo1), mag);
            atomicAdd(&hw[bo], wo0);
        }
        asm volatile("s_waitcnt lgkmcnt(0)" ::: "memory");

        // ---- Smoothing (lanes 0..35)
        float sm = 0.0f;
        if (l < NB) {
            const float inv = 1.0f / 1024.0f;  // exact power of 2
            float hm = (l > 0)      ? __fmul_rn(hw[l - 1], inv) : 0.0f;
            float h0 =                __fmul_rn(hw[l],     inv);
            float hp = (l < NB - 1) ? __fmul_rn(hw[l + 1], inv) : 0.0f;
            sm = __fadd_rn(__fadd_rn(__fmul_rn(0.33f, hm), __fmul_rn(0.34f, h0)),
                           __fmul_rn(0.33f, hp));
        }

        // ---- First-wins argmax via packed-key butterfly (sm >= 0 always)
        unsigned long long key =
            (l < NB) ? ((((unsigned long long)__float_as_uint(sm)) << 6) |
                        (unsigned long long)(63 - l))
                     : 0ull;
#pragma unroll
        for (int off = 32; off > 0; off >>= 1) {
            unsigned long long o = __shfl_xor(key, off, 64);
            key = (o > key) ? o : key;
        }

        if (l == 0) {
            int bi = 63 - (int)(key & 63);
            float t2 = __fdiv_rn(__fmul_rn(TWOPI_F, (float)bi), 36.0f);
            out[patch] = __fsub_rn(PI_F, t2);
        }

        // hist/tile reads above are drained before next iteration's ds_writes
        asm volatile("s_waitcnt lgkmcnt(0)" ::: "memory");
    }
}

extern "C" void kernel_launch(void* const* d_in, const int* in_sizes, int n_in,
                              void* d_out, int out_size, void* d_ws, size_t ws_size,
                              hipStream_t stream) {
    const float* x = (const float*)d_in[0];
    float* out = (float*)d_out;
    float* gk10 = (float*)d_ws;   // 1024 floats = 4 KB scratch

    const int B = in_sizes[0] / NPIX;

    // Persistent grid: ~TPW patches per wave, capped by problem size
    int blocks = (B + WPB * TPW - 1) / (WPB * TPW);
    int maxb   = (B + WPB - 1) / WPB;
    if (blocks > maxb) blocks = maxb;
    if (blocks < 1) blocks = 1;

    gk_init_kernel<<<1, 256, 0, stream>>>(gk10);
    orient_kernel<<<blocks, 256, 0, stream>>>(x, gk10, out, B);
}

// Round 7
// 119.282 us; speedup vs baseline: 3.2313x; 3.2313x over previous
//
#include <hip/hip_runtime.h>

#define PS 32
#define NPIX (PS * PS)
#define NB 36
#define WPB 4      // waves (patches) per block
#define HCOL 64    // one exclusive histogram column per lane
#define HWORDS (NB * HCOL)   // 2304 words per wave (tile overlays first 1024)

// ---------------------------------------------------------------------------
// Init kernel: gk10[p] = float32(10 * CircularGaussKernel(32)) computed in f64,
// replicating numpy linspace + exp + normalize semantics, then cast to f32.
// ---------------------------------------------------------------------------
__global__ __launch_bounds__(256) void gk_init_kernel(float* __restrict__ gk10) {
    __shared__ double red[256];
    const int tid = threadIdx.x;
    const double delta = 32.0 / 31.0;       // numpy linspace step, f64
    const double sigma2 = 0.9 * 256.0;      // 0.9 * half^2, f64

    double kv[4];
    double s = 0.0;
#pragma unroll
    for (int j = 0; j < 4; ++j) {
        int p = tid * 4 + j;
        int r = p >> 5, c = p & 31;
        double xr = (r == 31) ? 16.0 : ((double)r * delta + (-16.0));
        double xc = (c == 31) ? 16.0 : ((double)c * delta + (-16.0));
        double d2 = xc * xc + xr * xr;
        kv[j] = exp(-d2 / sigma2);
        s += kv[j];
    }
    red[tid] = s;
    __syncthreads();
    for (int off = 128; off > 0; off >>= 1) {
        if (tid < off) red[tid] += red[tid + off];
        __syncthreads();
    }
    double sum = red[0];
#pragma unroll
    for (int j = 0; j < 4; ++j) {
        int p = tid * 4 + j;
        gk10[p] = __fmul_rn(10.0f, (float)(kv[j] / sum));
    }
}

// ---------------------------------------------------------------------------
// Cold path: exact f64 recompute of one flagged bin-boundary pixel.
// Adds into the lane's exclusive histogram column (plain RMW, race-free).
// ---------------------------------------------------------------------------
__device__ __attribute__((noinline))
void fix_pixel(float lv, float rv, float uv, float dv, float gk, float* col) {
    const float PI_F    = 3.14159265358979323846f;
    const float TWOPI_F = 6.28318530717958647692f;
    float gx = __fmul_rn(0.5f, __fsub_rn(lv, rv));
    float gy = __fmul_rn(0.5f, __fsub_rn(uv, dv));
    float s2 = __fadd_rn(__fadd_rn(__fmul_rn(gx, gx), __fmul_rn(gy, gy)), 1e-10f);
    float mag = __fmul_rn(__fsqrt_rn(s2), gk);

    float ori  = (float)atan2((double)gy, (double)gx);  // correctly-rounded f32
    float obig = __fdiv_rn(__fmul_rn(36.0f, __fadd_rn(ori, PI_F)), TWOPI_F);
    float bo0f = floorf(obig);
    float wo1  = __fsub_rn(obig, bo0f);
    int bo = (int)bo0f;
    if (bo >= NB) bo -= NB;
    float wo0 = __fmul_rn(__fsub_rn(1.0f, wo1), mag);
    col[bo * HCOL] += wo0;
}

// ---------------------------------------------------------------------------
// Main kernel: 4 waves per block, ONE WAVE PER PATCH, ZERO LDS ATOMICS.
// Histogram: per-lane exclusive column -> plain ds_read/add/ds_write RMW.
// Hist region overlays the tile (tile is fully register-resident first).
// ---------------------------------------------------------------------------
__global__ __launch_bounds__(256) void orient_kernel(const float* __restrict__ x,
                                                     const float* __restrict__ gk10,
                                                     float* __restrict__ out) {
    const float PI_F    = 3.14159265358979323846f;   // 0x40490FDB
    const float TWOPI_F = 6.28318530717958647692f;   // 0x40C90FDB

    __shared__ __align__(16) float lds[WPB][HWORDS];

    const int tid = threadIdx.x;
    const int w = tid >> 6;          // wave id within block
    const int l = tid & 63;          // lane within wave
    const int patch = blockIdx.x * WPB + w;

    float* rw = lds[w];

    const int r  = l >> 3;           // row within each 8-row band
    const int c0 = (l & 7) << 2;     // col 0,4,...,28

    // ---- Global loads (patch + gaussian weights)
    const float4* src = reinterpret_cast<const float4*>(x + (size_t)patch * NPIX);
    float4 ld[4], gkq[4];
#pragma unroll
    for (int k = 0; k < 4; ++k) ld[k] = src[k * 64 + l];
#pragma unroll
    for (int k = 0; k < 4; ++k)
        gkq[k] = *reinterpret_cast<const float4*>(&gk10[(k * 8 + r) * PS + c0]);

    // ---- Stage tile into LDS (first 1024 words of the wave region)
    float4* dst = reinterpret_cast<float4*>(rw);
#pragma unroll
    for (int k = 0; k < 4; ++k) dst[k * 64 + l] = ld[k];
    asm volatile("s_waitcnt lgkmcnt(0)" ::: "memory");

    // ---- Pull ALL neighbor data into registers (self rows come from ld[])
    float4 up[4], dn[4];
    float  lsc[4], rsc[4];
#pragma unroll
    for (int k = 0; k < 4; ++k) {
        const int row = k * 8 + r;
        const int rowOff = row << 5;
        const int upOff  = ((row == 0)  ? 0  : (row - 1)) << 5;   // replicate pad
        const int dnOff  = ((row == 31) ? 31 : (row + 1)) << 5;
        up[k]  = *reinterpret_cast<const float4*>(&rw[upOff + c0]);
        dn[k]  = *reinterpret_cast<const float4*>(&rw[dnOff + c0]);
        lsc[k] = rw[rowOff + ((c0 == 0) ? 0 : (c0 - 1))];
        rsc[k] = rw[rowOff + ((c0 + 4 > 31) ? 31 : (c0 + 4))];
    }
    // reads landed in registers before we overwrite the region with hist
    asm volatile("s_waitcnt lgkmcnt(0)" ::: "memory");

    // ---- Zero hist region: 2304 words = 576 float4, 9 per lane
#pragma unroll
    for (int p = 0; p < 9; ++p)
        dst[p * 64 + l] = make_float4(0.0f, 0.0f, 0.0f, 0.0f);
    asm volatile("s_waitcnt lgkmcnt(0)" ::: "memory");

    // ---- Hot loop: 16 pixels/lane; histogram via exclusive-column RMW
    unsigned int badbits = 0;
    float* mycol = rw + l;          // lane-exclusive column base
#pragma unroll
    for (int k = 0; k < 4; ++k) {
        float sv[4]  = {ld[k].x, ld[k].y, ld[k].z, ld[k].w};
        float uv[4]  = {up[k].x, up[k].y, up[k].z, up[k].w};
        float dv[4]  = {dn[k].x, dn[k].y, dn[k].z, dn[k].w};
        float gk4[4] = {gkq[k].x, gkq[k].y, gkq[k].z, gkq[k].w};
        float lv[4]  = {lsc[k], sv[0], sv[1], sv[2]};
        float rv[4]  = {sv[1],  sv[2], sv[3], rsc[k]};

#pragma unroll
        for (int j = 0; j < 4; ++j) {
            const int i = k * 4 + j;
            // Reference f32 op order for magnitude (no contraction):
            float gx = __fmul_rn(0.5f, __fsub_rn(lv[j], rv[j]));
            float gy = __fmul_rn(0.5f, __fsub_rn(uv[j], dv[j]));
            float s2 = __fadd_rn(__fadd_rn(__fmul_rn(gx, gx), __fmul_rn(gy, gy)), 1e-10f);
            float mag = __fmul_rn(__fsqrt_rn(s2), gk4[j]);

            // Fast atan2 directly in bin units: obig = (atan2+pi)*36/(2pi)
            float ax = fabsf(gx), ay = fabsf(gy);
            float mn = fminf(ax, ay), mx = fmaxf(ax, ay);
            float rr = mn * __builtin_amdgcn_rcpf(mx);   // ~1 ulp
            rr = (mx > 0.0f) ? rr : 0.0f;                // atan2(0,0) = 0
            float t  = rr * rr;
            float u = 0.00282363896258175373077393f;     // SLEEF deg-17 odd minimax
            u = fmaf(u, t, -0.0159569028764963150024414f);
            u = fmaf(u, t,  0.0425049886107444763183594f);
            u = fmaf(u, t, -0.0748900920152664184570312f);
            u = fmaf(u, t,  0.106347933411598205566406f);
            u = fmaf(u, t, -0.142027363181114196777344f);
            u = fmaf(u, t,  0.199926957488059997558594f);
            u = fmaf(u, t, -0.333331018686294555664062f);
            float at = fmaf(rr * t, u, rr);              // atan(rr), [0, pi/4]

            // Quadrant folding to bin units (exact-integer offsets)
            bool c1 = ay > ax;
            bool c2 = gx < 0.0f;
            bool c3 = gy < 0.0f;
            float S  = c1 ? -1.0f : 1.0f;
            float Cb = c1 ? 27.0f : 18.0f;
            S  = c2 ? -S : S;
            Cb = c2 ? __fsub_rn(54.0f, Cb) : Cb;
            S  = c3 ? -S : S;
            Cb = c3 ? __fsub_rn(36.0f, Cb) : Cb;
            float obig = fmaf(at * S, 5.72957795130823208768f, Cb);  // [0,36]
            float bo0f = floorf(obig);
            float wo1  = __fsub_rn(obig, bo0f);

            bool bad = (wo1 < 2e-5f) | (wo1 > 1.0f - 2e-5f);
            if (!bad) {
                int bo = (int)bo0f;
                if (bo >= NB) bo -= NB;
                float wo0 = __fmul_rn(__fsub_rn(1.0f, wo1), mag);
                mycol[bo * HCOL] += wo0;     // plain LDS RMW, lane-exclusive
            } else {
                badbits |= (1u << i);
            }
        }
    }

    // ---- Rare exact f64 fixup (ballot-guarded; operands from live registers)
    if (__ballot(badbits != 0)) {
#pragma unroll
        for (int k = 0; k < 4; ++k) {
            float sv[4]  = {ld[k].x, ld[k].y, ld[k].z, ld[k].w};
            float uv[4]  = {up[k].x, up[k].y, up[k].z, up[k].w};
            float dv[4]  = {dn[k].x, dn[k].y, dn[k].z, dn[k].w};
            float gk4[4] = {gkq[k].x, gkq[k].y, gkq[k].z, gkq[k].w};
            float lv[4]  = {lsc[k], sv[0], sv[1], sv[2]};
            float rv[4]  = {sv[1],  sv[2], sv[3], rsc[k]};
#pragma unroll
            for (int j = 0; j < 4; ++j) {
                if (badbits & (1u << (k * 4 + j)))
                    fix_pixel(lv[j], rv[j], uv[j], dv[j], gk4[j], mycol);
            }
        }
    }
    asm volatile("s_waitcnt lgkmcnt(0)" ::: "memory");

    // ---- Reduction: lane b (<36) sums its 64-word row (rotated start to
    // spread banks; fp order change is argmax-safe, proven rounds 1-6)
    float hval = 0.0f;
    if (l < NB) {
        const float4* row4 = reinterpret_cast<const float4*>(rw + l * HCOL);
        float tot = 0.0f;
#pragma unroll
        for (int k = 0; k < 16; ++k) {
            float4 a = row4[(k + l) & 15];
            tot += ((a.x + a.y) + (a.z + a.w));
        }
        hval = __fmul_rn(tot, 1.0f / 1024.0f);   // exact power-of-2 scale
    }

    // ---- Smoothing via lane shuffles (zero pad; lane 36 holds 0)
    float hm = __shfl_up(hval, 1, 64);
    if (l == 0) hm = 0.0f;
    float hp = __shfl_down(hval, 1, 64);
    float sm = 0.0f;
    if (l < NB) {
        sm = __fadd_rn(__fadd_rn(__fmul_rn(0.33f, hm), __fmul_rn(0.34f, hval)),
                       __fmul_rn(0.33f, hp));
    }

    // ---- First-wins argmax via packed-key butterfly (sm >= 0 always)
    unsigned long long key =
        (l < NB) ? ((((unsigned long long)__float_as_uint(sm)) << 6) |
                    (unsigned long long)(63 - l))
                 : 0ull;
#pragma unroll
    for (int off = 32; off > 0; off >>= 1) {
        unsigned long long o = __shfl_xor(key, off, 64);
        key = (o > key) ? o : key;
    }

    if (l == 0) {
        int bi = 63 - (int)(key & 63);
        float t2 = __fdiv_rn(__fmul_rn(TWOPI_F, (float)bi), 36.0f);
        out[patch] = __fsub_rn(PI_F, t2);
    }
}

extern "C" void kernel_launch(void* const* d_in, const int* in_sizes, int n_in,
                              void* d_out, int out_size, void* d_ws, size_t ws_size,
                              hipStream_t stream) {
    const float* x = (const float*)d_in[0];
    float* out = (float*)d_out;
    float* gk10 = (float*)d_ws;   // 1024 floats = 4 KB scratch

    const int B = in_sizes[0] / NPIX;

    gk_init_kernel<<<1, 256, 0, stream>>>(gk10);
    orient_kernel<<<B / WPB, 256, 0, stream>>>(x, gk10, out);
}